// Round 1
// baseline (13696.046 us; speedup 1.0000x reference)
//
#include <hip/hip_runtime.h>
#include <math.h>

#define KNB 100
#define EDIM 64

// One block per batch row b. 256 threads = 4 waves.
// Phase 1: gather-sum user/item neighbor embeddings (waves split K).
// Phase 2: per-(b,e) MLP 2->20->200->200->20->1 with activations in LDS,
//          register-blocked over output neurons (10 acc per thread).
// Phase 3: mean over E=64 + sigmoid, wave-0 shuffle reduce.
__global__ __launch_bounds__(256, 1) void oneway_fused_kernel(
    const int* __restrict__ user_idxs, const int* __restrict__ item_idxs,
    const int* __restrict__ user_idx_tensor, const int* __restrict__ item_idx_tensor,
    const float* __restrict__ user_emb, const float* __restrict__ item_emb,
    const float* __restrict__ w1, const float* __restrict__ b1,
    const float* __restrict__ w2, const float* __restrict__ b2,
    const float* __restrict__ w3, const float* __restrict__ b3,
    const float* __restrict__ w4, const float* __restrict__ b4,
    const float* __restrict__ w5, const float* __restrict__ b5,
    float* __restrict__ out)
{
    const int b = blockIdx.x;
    const int tid = (int)threadIdx.x;
    const int lane = tid & 63;
    // wave id; readfirstlane makes it provably wave-uniform -> weight loads
    // become scalar (s_load) through the constant cache.
    const int w = __builtin_amdgcn_readfirstlane(tid >> 6);

    __shared__ float part_u[4][64];
    __shared__ float part_i[4][64];
    __shared__ float h1s[64 * 21];   // stride 21: gcd(21,32)=1 -> conflict-free
    __shared__ float h2s[64 * 201];  // stride 201: gcd(201,32)=1 -> conflict-free
    __shared__ float h3s[64 * 201];
    __shared__ float h4s[64 * 21];

    // ---- Phase 1: gather-sum --------------------------------------------
    {
        const int u  = user_idxs[b];
        const int it = item_idxs[b];
        float su = 0.f, si = 0.f;
        #pragma unroll 5
        for (int k = w; k < KNB; k += 4) {
            const int nb = user_idx_tensor[u * KNB + k];     // uniform (s_load)
            su += user_emb[nb * EDIM + lane];                // coalesced 256B row
        }
        #pragma unroll 5
        for (int k = w; k < KNB; k += 4) {
            const int nb = item_idx_tensor[it * KNB + k];
            si += item_emb[nb * EDIM + lane];
        }
        part_u[w][lane] = su;
        part_i[w][lane] = si;
    }
    __syncthreads();

    const float xu = part_u[0][lane] + part_u[1][lane] + part_u[2][lane] + part_u[3][lane];
    const float xv = part_i[0][lane] + part_i[1][lane] + part_i[2][lane] + part_i[3][lane];

    // ---- Layer 1: 2 -> 20 ------------------------------------------------
    #pragma unroll
    for (int jj = 0; jj < 5; ++jj) {
        const int j = w + 4 * jj;
        float acc = fmaf(xu, w1[j * 2 + 0], fmaf(xv, w1[j * 2 + 1], b1[j]));
        h1s[lane * 21 + j] = fmaxf(acc, 0.f);
    }
    __syncthreads();

    // ---- Layer 2: 20 -> 200 ---------------------------------------------
    for (int t = 0; t < 5; ++t) {
        const int jb = w + 4 * t;      // block of 10 output neurons
        float acc[10];
        #pragma unroll
        for (int jj = 0; jj < 10; ++jj) acc[jj] = b2[jb * 10 + jj];
        #pragma unroll 4
        for (int k = 0; k < 20; ++k) {
            const float hv = h1s[lane * 21 + k];
            #pragma unroll
            for (int jj = 0; jj < 10; ++jj)
                acc[jj] = fmaf(hv, w2[(jb * 10 + jj) * 20 + k], acc[jj]);
        }
        #pragma unroll
        for (int jj = 0; jj < 10; ++jj)
            h2s[lane * 201 + jb * 10 + jj] = fmaxf(acc[jj], 0.f);
    }
    __syncthreads();

    // ---- Layer 3: 200 -> 200 (dominant cost) ----------------------------
    for (int t = 0; t < 5; ++t) {
        const int jb = w + 4 * t;
        float acc[10];
        #pragma unroll
        for (int jj = 0; jj < 10; ++jj) acc[jj] = b3[jb * 10 + jj];
        #pragma unroll 4
        for (int k = 0; k < 200; ++k) {
            const float hv = h2s[lane * 201 + k];   // 1 LDS read feeds 10 FMAs
            #pragma unroll
            for (int jj = 0; jj < 10; ++jj)
                acc[jj] = fmaf(hv, w3[(jb * 10 + jj) * 200 + k], acc[jj]);
        }
        #pragma unroll
        for (int jj = 0; jj < 10; ++jj)
            h3s[lane * 201 + jb * 10 + jj] = fmaxf(acc[jj], 0.f);
    }
    __syncthreads();

    // ---- Layer 4: 200 -> 20 ---------------------------------------------
    {
        float acc[5];
        #pragma unroll
        for (int jj = 0; jj < 5; ++jj) acc[jj] = b4[w + 4 * jj];
        #pragma unroll 4
        for (int k = 0; k < 200; ++k) {
            const float hv = h3s[lane * 201 + k];
            #pragma unroll
            for (int jj = 0; jj < 5; ++jj)
                acc[jj] = fmaf(hv, w4[(w + 4 * jj) * 200 + k], acc[jj]);
        }
        #pragma unroll
        for (int jj = 0; jj < 5; ++jj)
            h4s[lane * 21 + w + 4 * jj] = fmaxf(acc[jj], 0.f);
    }
    __syncthreads();

    // ---- Layer 5 (20 -> 1) + mean over E + sigmoid ----------------------
    if (w == 0) {
        float acc = b5[0];
        #pragma unroll
        for (int k = 0; k < 20; ++k)
            acc = fmaf(h4s[lane * 21 + k], w5[k], acc);
        // sum over the 64 "e" lanes
        #pragma unroll
        for (int off = 32; off; off >>= 1)
            acc += __shfl_xor(acc, off);
        if (lane == 0) {
            const float m = acc * (1.0f / 64.0f);
            out[b] = 1.0f / (1.0f + expf(-m));
        }
    }
}

extern "C" void kernel_launch(void* const* d_in, const int* in_sizes, int n_in,
                              void* d_out, int out_size, void* d_ws, size_t ws_size,
                              hipStream_t stream) {
    const int*   user_idxs       = (const int*)d_in[0];
    const int*   item_idxs       = (const int*)d_in[1];
    const int*   user_idx_tensor = (const int*)d_in[2];
    const int*   item_idx_tensor = (const int*)d_in[3];
    const float* user_emb        = (const float*)d_in[4];
    const float* item_emb        = (const float*)d_in[5];
    const float* w1 = (const float*)d_in[6];
    const float* b1 = (const float*)d_in[7];
    const float* w2 = (const float*)d_in[8];
    const float* b2 = (const float*)d_in[9];
    const float* w3 = (const float*)d_in[10];
    const float* b3 = (const float*)d_in[11];
    const float* w4 = (const float*)d_in[12];
    const float* b4 = (const float*)d_in[13];
    const float* w5 = (const float*)d_in[14];
    const float* b5 = (const float*)d_in[15];
    float* out = (float*)d_out;

    const int B = in_sizes[0];  // 32768
    hipLaunchKernelGGL(oneway_fused_kernel, dim3(B), dim3(256), 0, stream,
                       user_idxs, item_idxs, user_idx_tensor, item_idx_tensor,
                       user_emb, item_emb,
                       w1, b1, w2, b2, w3, b3, w4, b4, w5, b5, out);
}

// Round 2
// 2796.992 us; speedup vs baseline: 4.8967x; 4.8967x over previous
//
#include <hip/hip_runtime.h>
#include <math.h>

typedef short v8s __attribute__((ext_vector_type(8)));
typedef float v4f __attribute__((ext_vector_type(4)));

#define MFMA16(a,b,c) __builtin_amdgcn_mfma_f32_16x16x32_bf16((a),(b),(c),0,0,0)

// ---------------- workspace layout (bytes) ----------------
// w3 as 7 K-chunks of [208 j][32 k] bf16 (k-chunk ksc covers k=32*ksc..+31)
#define W3B_CHUNK  (208*32)                     // elems per chunk
#define OFF_W3B    0
#define OFF_W2B    (OFF_W3B + 7*W3B_CHUNK*2)    // [208 j][32 k] bf16 (k pad 20->32)
#define OFF_W4B    (OFF_W2B + 208*32*2)         // [32 j][224 k] bf16
#define OFF_B2B    (OFF_W4B + 32*224*2)         // [208] f32
#define OFF_B3B    (OFF_B2B + 208*4)            // [224] f32
#define OFF_B4B    (OFF_B3B + 224*4)            // [32] f32
#define OFF_W5B    (OFF_B4B + 32*4)             // [32] f32

__device__ __forceinline__ unsigned short f2bf(float f) {
    union { float f; unsigned int u; } v; v.f = f;
    unsigned int u = v.u + 0x7FFFu + ((v.u >> 16) & 1u);   // RNE
    return (unsigned short)(u >> 16);
}

// ---------------- prep: fp32 weights -> padded bf16 in ws ----------------
__global__ void prep_kernel(const float* __restrict__ w2, const float* __restrict__ w3,
                            const float* __restrict__ w4, const float* __restrict__ b2,
                            const float* __restrict__ b3, const float* __restrict__ b4,
                            const float* __restrict__ w5, char* __restrict__ ws) {
    unsigned short* w3b = (unsigned short*)(ws + OFF_W3B);
    unsigned short* w2b = (unsigned short*)(ws + OFF_W2B);
    unsigned short* w4b = (unsigned short*)(ws + OFF_W4B);
    float* b2b = (float*)(ws + OFF_B2B);
    float* b3b = (float*)(ws + OFF_B3B);
    float* b4b = (float*)(ws + OFF_B4B);
    float* w5b = (float*)(ws + OFF_W5B);

    const int gid = blockIdx.x * blockDim.x + threadIdx.x;
    const int stride = gridDim.x * blockDim.x;

    for (int i = gid; i < 7*W3B_CHUNK; i += stride) {
        int ksc = i / W3B_CHUNK, r = i % W3B_CHUNK;
        int j = r >> 5, kk = r & 31, k = 32*ksc + kk;
        float v = (j < 200 && k < 200) ? w3[j*200 + k] : 0.f;
        w3b[i] = f2bf(v);
    }
    for (int i = gid; i < 208*32; i += stride) {
        int j = i >> 5, k = i & 31;
        w2b[i] = f2bf((j < 200 && k < 20) ? w2[j*20 + k] : 0.f);
    }
    for (int i = gid; i < 32*224; i += stride) {
        int j = i / 224, k = i % 224;
        w4b[i] = f2bf((j < 20 && k < 200) ? w4[j*200 + k] : 0.f);
    }
    for (int i = gid; i < 208; i += stride) b2b[i] = (i < 200) ? b2[i] : 0.f;
    for (int i = gid; i < 224; i += stride) b3b[i] = (i < 200) ? b3[i] : 0.f;
    for (int i = gid; i < 32;  i += stride) b4b[i] = (i < 20) ? b4[i] : 0.f;
    for (int i = gid; i < 32;  i += stride) w5b[i] = (i < 20) ? w5[i] : 0.f;
}

// ---------------- fused main kernel ----------------
// Block: 4 batch rows (b) x 64 e = 256 MLP rows, 512 threads = 8 waves.
// Wave wv owns rows 32*wv .. 32*wv+31 (two 16-row M-tiles).
#define H1_STRIDE 40   // bf16 elems per row (20 real + 12 zero-pad k + 8 slack)
#define H2_STRIDE 232  // bf16 elems per row (200 real + 24 zero-pad k + 8 slack)

__global__ __launch_bounds__(512, 2) void fused_kernel(
    const int* __restrict__ user_idxs, const int* __restrict__ item_idxs,
    const int* __restrict__ uidx, const int* __restrict__ iidx,
    const float* __restrict__ uemb, const float* __restrict__ iemb,
    const float* __restrict__ w1, const float* __restrict__ b1,
    const float* __restrict__ b5p, const char* __restrict__ ws,
    float* __restrict__ out, int B)
{
    __shared__ unsigned short h2s[256 * H2_STRIDE];   // 118784 B
    __shared__ unsigned short wbs[208 * 32];          // 13312 B (w2 / w3-chunk stage)
    __shared__ unsigned short h1s[256 * H1_STRIDE];   // 20480 B (reused as scratch)
    __shared__ float xbuf[8][64];                     // 2048 B (reused as mbuf)

    const int tid  = (int)threadIdx.x;
    const int lane = tid & 63;
    const int wv   = __builtin_amdgcn_readfirstlane(tid >> 6);
    const int bbase = blockIdx.x << 2;

    const unsigned short* w3b = (const unsigned short*)(ws + OFF_W3B);
    const unsigned short* w2b = (const unsigned short*)(ws + OFF_W2B);
    const unsigned short* w4b = (const unsigned short*)(ws + OFF_W4B);
    const float* b2b = (const float*)(ws + OFF_B2B);
    const float* b3b = (const float*)(ws + OFF_B3B);
    const float* b4b = (const float*)(ws + OFF_B4B);
    const float* w5b = (const float*)(ws + OFF_W5B);

    // ---- Phase 1: gather-sum. wave -> (b_local = wv>>1, table = wv&1) ----
    {
        int b = bbase + (wv >> 1); if (b >= B) b = B - 1;
        const int*   ntab = (wv & 1) ? iidx : uidx;
        const float* emb  = (wv & 1) ? iemb : uemb;
        const int idx0 = (wv & 1) ? item_idxs[b] : user_idxs[b];
        const int* nrow = ntab + idx0 * 100;
        float s0 = 0.f, s1 = 0.f, s2 = 0.f, s3 = 0.f;
        #pragma unroll 2
        for (int k = 0; k < 100; k += 4) {
            int4 n4 = *(const int4*)(nrow + k);       // uniform -> s_load_dwordx4
            s0 += emb[(size_t)n4.x * 64 + lane];      // coalesced 256B rows
            s1 += emb[(size_t)n4.y * 64 + lane];
            s2 += emb[(size_t)n4.z * 64 + lane];
            s3 += emb[(size_t)n4.w * 64 + lane];
        }
        xbuf[wv][lane] = (s0 + s1) + (s2 + s3);
    }
    __syncthreads();

    // ---- Layer 1 (2 -> 20, fp32 VALU) -> h1s bf16 [row][40], k-pad zeroed ----
    {
        const int row = tid >> 1, half = tid & 1;
        const int bl = row >> 6, e = row & 63;
        const float xu = xbuf[2*bl][e], xv = xbuf[2*bl+1][e];
        unsigned int* dst = (unsigned int*)(h1s + row*H1_STRIDE + half*10);
        #pragma unroll
        for (int jj = 0; jj < 10; jj += 2) {
            const int j = half*10 + jj;
            float a0 = fmaxf(fmaf(xu, w1[2*j],   fmaf(xv, w1[2*j+1], b1[j])),   0.f);
            float a1 = fmaxf(fmaf(xu, w1[2*j+2], fmaf(xv, w1[2*j+3], b1[j+1])), 0.f);
            dst[jj >> 1] = (unsigned int)f2bf(a0) | ((unsigned int)f2bf(a1) << 16);
        }
        unsigned int* dz = (unsigned int*)(h1s + row*H1_STRIDE + 20 + half*10);
        #pragma unroll
        for (int z = 0; z < 5; ++z) dz[z] = 0u;
    }

    const int c = lane & 15;      // fragment col / A-row sub-index
    const int g = lane >> 4;      // fragment k-group / D-row group

    // ---- Layer 2 (20 -> 200 MFMA): stage w2b, compute own 32 rows ----
    __syncthreads();
    for (int s = tid; s < 832; s += 512)                       // 13312 B
        *(v8s*)(wbs + s*8) = *(const v8s*)(w2b + s*8);
    __syncthreads();
    {
        #pragma unroll
        for (int m = 0; m < 2; ++m) {
            const int rowb = 32*wv + 16*m;
            v8s af = *(const v8s*)(h1s + (rowb + c)*H1_STRIDE + 8*g);
            for (int nt = 0; nt < 13; ++nt) {
                v8s bf = *(const v8s*)(wbs + (16*nt + c)*32 + 8*g);
                v4f acc = {0.f, 0.f, 0.f, 0.f};
                acc = MFMA16(af, bf, acc);
                const float bias = b2b[16*nt + c];
                #pragma unroll
                for (int q = 0; q < 4; ++q)
                    h2s[(rowb + 4*g + q)*H2_STRIDE + 16*nt + c] =
                        f2bf(fmaxf(acc[q] + bias, 0.f));
            }
        }
        // zero k-pad cols 200..231 of own rows
        const int rr = 32*wv + (lane >> 1);
        v8s zv = {0,0,0,0,0,0,0,0};
        unsigned short* pz = h2s + rr*H2_STRIDE + 200 + 16*(lane & 1);
        *(v8s*)pz = zv; *(v8s*)(pz + 8) = zv;
    }

    // ---- Layer 3 (200 -> 200 MFMA), acc over 7 K-chunks of 32 ----
    v4f acc3[2][13];
    #pragma unroll
    for (int m = 0; m < 2; ++m)
        #pragma unroll
        for (int nt = 0; nt < 13; ++nt) acc3[m][nt] = (v4f){0.f,0.f,0.f,0.f};

    for (int ksc = 0; ksc < 7; ++ksc) {
        __syncthreads();
        {
            const unsigned short* src = w3b + ksc*W3B_CHUNK;
            for (int s = tid; s < 832; s += 512)
                *(v8s*)(wbs + s*8) = *(const v8s*)(src + s*8);
        }
        __syncthreads();
        v8s bf[13];
        #pragma unroll
        for (int nt = 0; nt < 13; ++nt)
            bf[nt] = *(const v8s*)(wbs + (16*nt + c)*32 + 8*g);
        #pragma unroll
        for (int m = 0; m < 2; ++m) {
            v8s af = *(const v8s*)(h2s + (32*wv + 16*m + c)*H2_STRIDE + 32*ksc + 8*g);
            #pragma unroll
            for (int nt = 0; nt < 13; ++nt)
                acc3[m][nt] = MFMA16(af, bf[nt], acc3[m][nt]);
        }
    }

    // ---- Layer 3 epilogue + Layer 4 (200 -> 20 MFMA), fused via per-wave
    //      16x32 transpose scratch in the (dead) h1s region ----
    v4f acc4[2][2];
    #pragma unroll
    for (int m = 0; m < 2; ++m) { acc4[m][0] = (v4f){0,0,0,0}; acc4[m][1] = (v4f){0,0,0,0}; }

    #pragma unroll 1
    for (int p = 0; p < 7; ++p) {          // layer-4 k-step = 32 = 2 N-tiles of h3
        #pragma unroll
        for (int m = 0; m < 2; ++m) {
            unsigned short* scr = h1s + wv*2560/2*2 + wv*0 + (wv*2560 + m*1280)/2; // elems
            // (simplified below)
            scr = h1s + wv*1280 + m*640;
            #pragma unroll
            for (int t = 0; t < 2; ++t) {
                const int nt = 2*p + t;
                if (nt < 13) {
                    const float bias = b3b[16*nt + c];
                    #pragma unroll
                    for (int q = 0; q < 4; ++q)
                        scr[(4*g + q)*40 + 16*t + c] =
                            f2bf(fmaxf(acc3[m][nt][q] + bias, 0.f));
                }
                // nt==13 (p==6,t==1): stale finite scratch x zero w4b rows -> 0
            }
            v8s a4  = *(const v8s*)(scr + c*40 + 8*g);
            v8s b40 = *(const v8s*)(w4b + c*224        + 32*p + 8*g);
            v8s b41 = *(const v8s*)(w4b + (c+16)*224   + 32*p + 8*g);
            acc4[m][0] = MFMA16(a4, b40, acc4[m][0]);
            acc4[m][1] = MFMA16(a4, b41, acc4[m][1]);
        }
    }

    // ---- Layer 4 epilogue + Layer 5 (20 -> 1) + per-row value -> mbuf ----
    float* mbuf = (float*)xbuf;            // xbuf dead; 256 f32
    {
        const float w5lo = w5b[c], w5hi = w5b[c + 16];
        const float b4lo = b4b[c], b4hi = b4b[c + 16];
        #pragma unroll
        for (int m = 0; m < 2; ++m) {
            float pr[4];
            #pragma unroll
            for (int q = 0; q < 4; ++q) {
                float h40 = fmaxf(acc4[m][0][q] + b4lo, 0.f);
                float h41 = fmaxf(acc4[m][1][q] + b4hi, 0.f);
                pr[q] = fmaf(h40, w5lo, h41 * w5hi);
            }
            #pragma unroll
            for (int off = 1; off < 16; off <<= 1) {
                #pragma unroll
                for (int q = 0; q < 4; ++q) pr[q] += __shfl_xor(pr[q], off);
            }
            if (c == 0) {
                float4 v4; v4.x = pr[0]; v4.y = pr[1]; v4.z = pr[2]; v4.w = pr[3];
                *(float4*)(mbuf + 32*wv + 16*m + 4*g) = v4;
            }
        }
    }
    __syncthreads();

    // ---- mean over E=64 + sigmoid; wave w' (0..3) reduces rows of b_local=w' ----
    if (tid < 256) {
        float v = mbuf[tid];
        #pragma unroll
        for (int off = 1; off < 64; off <<= 1) v += __shfl_xor(v, off);
        const int b = bbase + (tid >> 6);
        if ((tid & 63) == 0 && b < B) {
            const float mval = v * (1.0f / 64.0f) + b5p[0];
            out[b] = 1.0f / (1.0f + expf(-mval));
        }
    }
}

extern "C" void kernel_launch(void* const* d_in, const int* in_sizes, int n_in,
                              void* d_out, int out_size, void* d_ws, size_t ws_size,
                              hipStream_t stream) {
    const int*   user_idxs = (const int*)d_in[0];
    const int*   item_idxs = (const int*)d_in[1];
    const int*   uidx      = (const int*)d_in[2];
    const int*   iidx      = (const int*)d_in[3];
    const float* uemb      = (const float*)d_in[4];
    const float* iemb      = (const float*)d_in[5];
    const float* w1 = (const float*)d_in[6];
    const float* b1 = (const float*)d_in[7];
    const float* w2 = (const float*)d_in[8];
    const float* b2 = (const float*)d_in[9];
    const float* w3 = (const float*)d_in[10];
    const float* b3 = (const float*)d_in[11];
    const float* w4 = (const float*)d_in[12];
    const float* b4 = (const float*)d_in[13];
    const float* w5 = (const float*)d_in[14];
    const float* b5 = (const float*)d_in[15];
    float* out = (float*)d_out;
    char* ws = (char*)d_ws;

    const int B = in_sizes[0];

    hipLaunchKernelGGL(prep_kernel, dim3(256), dim3(256), 0, stream,
                       w2, w3, w4, b2, b3, b4, w5, ws);

    const int nblocks = (B + 3) >> 2;
    hipLaunchKernelGGL(fused_kernel, dim3(nblocks), dim3(512), 0, stream,
                       user_idxs, item_idxs, uidx, iidx, uemb, iemb,
                       w1, b1, b5, ws, out, B);
}

// Round 3
// 869.176 us; speedup vs baseline: 15.7575x; 3.2180x over previous
//
#include <hip/hip_runtime.h>
#include <math.h>

typedef short v8s __attribute__((ext_vector_type(8)));
typedef float v4f __attribute__((ext_vector_type(4)));
typedef unsigned short us;

#define MFMA16(a,b,c) __builtin_amdgcn_mfma_f32_16x16x32_bf16((a),(b),(c),0,0,0)

// ---------------- workspace layout ----------------
// w3b: 7 chunks [208 j][40 k-pad] bf16 (chunk ksc holds k = 32*ksc + kk, kk<32 real)
// w2b: [208 j][40 k] bf16 (k<20 real)      w4b: [32 j4][224 k] bf16
#define WCH (208*40)
#define OFF_W3B 0
#define OFF_W2B (OFF_W3B + 7*WCH*2)
#define OFF_W4B (OFF_W2B + WCH*2)
#define OFF_B2B (OFF_W4B + 32*224*2)
#define OFF_B3B (OFF_B2B + 208*4)
#define OFF_B4B (OFF_B3B + 224*4)
#define OFF_W5B (OFF_B4B + 32*4)

__device__ __forceinline__ us f2bf(float f) {
    union { float f; unsigned int u; } v; v.f = f;
    unsigned int u = v.u + 0x7FFFu + ((v.u >> 16) & 1u);   // RNE
    return (us)(u >> 16);
}
__device__ __forceinline__ unsigned int pack2bf(float a, float b) {
    return (unsigned int)f2bf(a) | ((unsigned int)f2bf(b) << 16);
}

// ---------------- prep: fp32 weights -> padded bf16 in ws ----------------
__global__ void prep_kernel(const float* __restrict__ w2, const float* __restrict__ w3,
                            const float* __restrict__ w4, const float* __restrict__ b2,
                            const float* __restrict__ b3, const float* __restrict__ b4,
                            const float* __restrict__ w5, char* __restrict__ ws) {
    us* w3b = (us*)(ws + OFF_W3B);
    us* w2b = (us*)(ws + OFF_W2B);
    us* w4b = (us*)(ws + OFF_W4B);
    float* b2b = (float*)(ws + OFF_B2B);
    float* b3b = (float*)(ws + OFF_B3B);
    float* b4b = (float*)(ws + OFF_B4B);
    float* w5b = (float*)(ws + OFF_W5B);

    const int gid = blockIdx.x * blockDim.x + threadIdx.x;
    const int stride = gridDim.x * blockDim.x;

    for (int i = gid; i < 7*WCH; i += stride) {
        int ksc = i / WCH, r = i % WCH;
        int j = r / 40, kk = r % 40, k = 32*ksc + kk;
        w3b[i] = f2bf((j < 200 && kk < 32 && k < 200) ? w3[j*200 + k] : 0.f);
    }
    for (int i = gid; i < WCH; i += stride) {
        int j = i / 40, kk = i % 40;
        w2b[i] = f2bf((j < 200 && kk < 20) ? w2[j*20 + kk] : 0.f);
    }
    for (int i = gid; i < 32*224; i += stride) {
        int j = i / 224, k = i % 224;
        w4b[i] = f2bf((j < 20 && k < 200) ? w4[j*200 + k] : 0.f);
    }
    for (int i = gid; i < 208; i += stride) b2b[i] = (i < 200) ? b2[i] : 0.f;
    for (int i = gid; i < 224; i += stride) b3b[i] = (i < 200) ? b3[i] : 0.f;
    for (int i = gid; i < 32;  i += stride) b4b[i] = (i < 20) ? b4[i] : 0.f;
    for (int i = gid; i < 32;  i += stride) w5b[i] = (i < 20) ? w5[i] : 0.f;
}

// ---------------- fused main kernel ----------------
// Block: 4 batch rows x 64 e = 256 MLP rows ("cols" of the MFMA), 512 thr = 8 waves.
// Wave wv owns MLP rows 32*wv..32*wv+31 (two 16-col tiles m=0,1).
// MFMA convention: A = weights [out-feature][k], B = activations [k][mlp-row],
//                  D = [out-feature][mlp-row]  -> lane holds 4 consecutive features.
#define H2S 232   // h2s row stride (elems); 464 B -> dword stride 116 = 20 mod 32 (bank-ok)

__global__ __launch_bounds__(512, 2) void fused_kernel(
    const int* __restrict__ user_idxs, const int* __restrict__ item_idxs,
    const int* __restrict__ uidx, const int* __restrict__ iidx,
    const float* __restrict__ uemb, const float* __restrict__ iemb,
    const float* __restrict__ w1, const float* __restrict__ b1,
    const float* __restrict__ b5p, const char* __restrict__ ws,
    float* __restrict__ out, int B)
{
    __shared__ us h2s[256 * H2S];     // 118784 B : h2 activations [row][feature]
    __shared__ us wbs0[WCH];          //  16640 B : w3 chunk buffer (even ksc)
    __shared__ us reg2[256 * 40];     //  20480 B : h1s, then w3 buffer (odd ksc), then scr
    __shared__ float xbuf[8][64];     //   2048 B : gather sums, then mbuf
                                      // total 157952 <= 160K -> 1 block/CU, 2 waves/SIMD

    const int tid  = (int)threadIdx.x;
    const int lane = tid & 63;
    const int wv   = __builtin_amdgcn_readfirstlane(tid >> 6);
    const int bbase = blockIdx.x << 2;

    const us* w3b = (const us*)(ws + OFF_W3B);
    const us* w2b = (const us*)(ws + OFF_W2B);
    const us* w4b = (const us*)(ws + OFF_W4B);
    const float* b2b = (const float*)(ws + OFF_B2B);
    const float* b3b = (const float*)(ws + OFF_B3B);
    const float* b4b = (const float*)(ws + OFF_B4B);
    const float* w5b = (const float*)(ws + OFF_W5B);

    // ---- prefetch w3 chunk 0 into regs (T14 issue-early) -----------------
    const int slot0 = tid, slot1 = 512 + tid, slot2 = 1024 + tid;  // of 1040 16B-slots
    v8s st0 = *(const v8s*)(w3b + slot0*8);
    v8s st1 = *(const v8s*)(w3b + slot1*8);
    v8s st2 = {};
    if (tid < 16) st2 = *(const v8s*)(w3b + slot2*8);

    // ---- Phase 1: gather-sum; wave -> (b_local = wv>>1, table = wv&1) ----
    {
        int b = bbase + (wv >> 1); if (b >= B) b = B - 1;
        const int*   ntab = (wv & 1) ? iidx : uidx;
        const float* emb  = (wv & 1) ? iemb : uemb;
        const int idx0 = (wv & 1) ? item_idxs[b] : user_idxs[b];
        const int* nrow = ntab + idx0 * 100;
        float s0 = 0.f, s1 = 0.f, s2 = 0.f, s3 = 0.f;
        #pragma unroll 2
        for (int k = 0; k < 100; k += 4) {
            int4 n4 = *(const int4*)(nrow + k);      // uniform -> s_load
            s0 += emb[(size_t)n4.x * 64 + lane];     // coalesced 256B rows
            s1 += emb[(size_t)n4.y * 64 + lane];
            s2 += emb[(size_t)n4.z * 64 + lane];
            s3 += emb[(size_t)n4.w * 64 + lane];
        }
        xbuf[wv][lane] = (s0 + s1) + (s2 + s3);
    }
    __syncthreads();

    // ---- Layer 1 (2->20 fp32) -> reg2 as h1s [row][40], k 20..39 zeroed ---
    {
        const int row = tid >> 1, half = tid & 1;
        const int bl = row >> 6, e = row & 63;
        const float xu = xbuf[2*bl][e], xv = xbuf[2*bl+1][e];
        unsigned int* dst = (unsigned int*)(reg2 + row*40 + half*10);
        #pragma unroll
        for (int jj = 0; jj < 10; jj += 2) {
            const int j = half*10 + jj;
            float a0 = fmaxf(fmaf(xu, w1[2*j],   fmaf(xv, w1[2*j+1], b1[j])),   0.f);
            float a1 = fmaxf(fmaf(xu, w1[2*j+2], fmaf(xv, w1[2*j+3], b1[j+1])), 0.f);
            dst[jj >> 1] = pack2bf(a0, a1);
        }
        unsigned int* dz = (unsigned int*)(reg2 + row*40 + 20 + half*10);
        #pragma unroll
        for (int z = 0; z < 5; ++z) dz[z] = 0u;
    }
    __syncthreads();

    const int c = lane & 15;      // A-row / D-col sub-index
    const int g = lane >> 4;      // k-group / D-row group

    // ---- Layer 2 (20->200): A = w2b (global, L2), B = h1s, D -> h2s -------
    {
        v8s af2[13];
        #pragma unroll
        for (int nt = 0; nt < 13; ++nt)
            af2[nt] = *(const v8s*)(w2b + (16*nt + c)*40 + 8*g);
        #pragma unroll
        for (int m = 0; m < 2; ++m) {
            const int col = 32*wv + 16*m + c;            // mlp row
            v8s bf = *(const v8s*)(reg2 + col*40 + 8*g);
            #pragma unroll
            for (int nt = 0; nt < 13; ++nt) {
                v4f acc = {0.f,0.f,0.f,0.f};
                acc = MFMA16(af2[nt], bf, acc);
                float4 bv = *(const float4*)(b2b + 16*nt + 4*g);
                unsigned int* p = (unsigned int*)(h2s + col*H2S + 16*nt + 4*g);
                p[0] = pack2bf(fmaxf(acc[0]+bv.x,0.f), fmaxf(acc[1]+bv.y,0.f));
                p[1] = pack2bf(fmaxf(acc[2]+bv.z,0.f), fmaxf(acc[3]+bv.w,0.f));
            }
        }
        // zero k-pad cols 200..231 of own 32 rows
        const int rr = 32*wv + (lane >> 1);
        v8s zv = {};
        us* pz = h2s + rr*H2S + 200 + 16*(lane & 1);
        *(v8s*)pz = zv; *(v8s*)(pz + 8) = zv;
    }
    __syncthreads();   // h2s visible; h1s dead; (also drains chunk-0 loads)

    // ---- Layer 3 (200->200): 7 K-chunks, reg-staged double buffer ---------
    v4f acc3[2][13];
    #pragma unroll
    for (int m = 0; m < 2; ++m)
        #pragma unroll
        for (int nt = 0; nt < 13; ++nt) acc3[m][nt] = (v4f){0.f,0.f,0.f,0.f};

    #pragma unroll 1
    for (int ksc = 0; ksc < 7; ++ksc) {
        us* buf = (ksc & 1) ? reg2 : wbs0;
        // write staged chunk ksc to LDS
        *(v8s*)(buf + slot0*8) = st0;
        *(v8s*)(buf + slot1*8) = st1;
        if (tid < 16) *(v8s*)(buf + slot2*8) = st2;
        // issue prefetch of chunk ksc+1 (hidden under MFMAs below)
        if (ksc < 6) {
            const us* src = w3b + (ksc+1)*WCH;
            st0 = *(const v8s*)(src + slot0*8);
            st1 = *(const v8s*)(src + slot1*8);
            if (tid < 16) st2 = *(const v8s*)(src + slot2*8);
        }
        __syncthreads();   // chunk ksc visible to all waves

        v8s af[13];
        #pragma unroll
        for (int nt = 0; nt < 13; ++nt)
            af[nt] = *(const v8s*)(buf + (16*nt + c)*40 + 8*g);
        #pragma unroll
        for (int m = 0; m < 2; ++m) {
            v8s bf = *(const v8s*)(h2s + (32*wv + 16*m + c)*H2S + 32*ksc + 8*g);
            #pragma unroll
            for (int nt = 0; nt < 13; ++nt)
                acc3[m][nt] = MFMA16(af[nt], bf, acc3[m][nt]);
        }
        __syncthreads();   // all waves done reading buf before it is rewritten
    }

    // ---- Layer 3 epilogue + Layer 4 (200->20), fused, FULLY UNROLLED ------
    // (runtime-indexed acc3 would demote to scratch: rule #20 / round-2 bug)
    us* scr = reg2 + wv*1280;           // per-wave private: 2 slices of [16 col][40]
    v4f acc4[2][2];
    acc4[0][0] = (v4f){0,0,0,0}; acc4[0][1] = (v4f){0,0,0,0};
    acc4[1][0] = (v4f){0,0,0,0}; acc4[1][1] = (v4f){0,0,0,0};

    #pragma unroll
    for (int p = 0; p < 7; ++p) {       // layer-4 k-step = 32 = 2 h3 feature-tiles
        v8s a40 = *(const v8s*)(w4b + c*224        + 32*p + 8*g);
        v8s a41 = *(const v8s*)(w4b + (c+16)*224   + 32*p + 8*g);
        #pragma unroll
        for (int m = 0; m < 2; ++m) {
            us* s = scr + m*640;
            #pragma unroll
            for (int t = 0; t < 2; ++t) {
                const int nt = 2*p + t;
                unsigned int* pp = (unsigned int*)(s + c*40 + 16*t + 4*g);
                if (nt < 13) {
                    float4 bv = *(const float4*)(b3b + 16*nt + 4*g);
                    pp[0] = pack2bf(fmaxf(acc3[m][nt][0]+bv.x,0.f),
                                    fmaxf(acc3[m][nt][1]+bv.y,0.f));
                    pp[1] = pack2bf(fmaxf(acc3[m][nt][2]+bv.z,0.f),
                                    fmaxf(acc3[m][nt][3]+bv.w,0.f));
                } else {                 // nt==13: zero pad (w4b also 0 there)
                    pp[0] = 0u; pp[1] = 0u;
                }
            }
            v8s b4f = *(const v8s*)(s + c*40 + 8*g);   // same-wave LDS dep
            acc4[m][0] = MFMA16(a40, b4f, acc4[m][0]);
            acc4[m][1] = MFMA16(a41, b4f, acc4[m][1]);
        }
    }

    // ---- Layer 4 epilogue + Layer 5 (20->1) -> per-row value --------------
    float* mbuf = (float*)xbuf;          // xbuf dead
    {
        float4 b4lo = *(const float4*)(b4b + 4*g);
        float4 b4hi = *(const float4*)(b4b + 16 + 4*g);
        float4 w5lo = *(const float4*)(w5b + 4*g);
        float4 w5hi = *(const float4*)(w5b + 16 + 4*g);
        #pragma unroll
        for (int m = 0; m < 2; ++m) {
            float sacc = 0.f;
            #pragma unroll
            for (int q = 0; q < 4; ++q) {
                float h0 = fmaxf(acc4[m][0][q] + ((const float*)&b4lo)[q], 0.f);
                float h1 = fmaxf(acc4[m][1][q] + ((const float*)&b4hi)[q], 0.f);
                sacc = fmaf(h0, ((const float*)&w5lo)[q],
                       fmaf(h1, ((const float*)&w5hi)[q], sacc));
            }
            sacc += __shfl_xor(sacc, 16);
            sacc += __shfl_xor(sacc, 32);      // sum over 4 g-groups
            if (lane < 16)
                mbuf[32*wv + 16*m + c] = sacc;
        }
    }
    __syncthreads();

    // ---- mean over E=64 + sigmoid ------------------------------------------
    if (tid < 256) {
        float v = mbuf[tid];
        #pragma unroll
        for (int off = 1; off < 64; off <<= 1) v += __shfl_xor(v, off);
        const int b = bbase + (tid >> 6);
        if ((tid & 63) == 0 && b < B) {
            const float mval = v * (1.0f / 64.0f) + b5p[0];
            out[b] = 1.0f / (1.0f + expf(-mval));
        }
    }
}

extern "C" void kernel_launch(void* const* d_in, const int* in_sizes, int n_in,
                              void* d_out, int out_size, void* d_ws, size_t ws_size,
                              hipStream_t stream) {
    const int*   user_idxs = (const int*)d_in[0];
    const int*   item_idxs = (const int*)d_in[1];
    const int*   uidx      = (const int*)d_in[2];
    const int*   iidx      = (const int*)d_in[3];
    const float* uemb      = (const float*)d_in[4];
    const float* iemb      = (const float*)d_in[5];
    const float* w1 = (const float*)d_in[6];
    const float* b1 = (const float*)d_in[7];
    const float* w2 = (const float*)d_in[8];
    const float* b2 = (const float*)d_in[9];
    const float* w3 = (const float*)d_in[10];
    const float* b3 = (const float*)d_in[11];
    const float* w4 = (const float*)d_in[12];
    const float* b4 = (const float*)d_in[13];
    const float* w5 = (const float*)d_in[14];
    const float* b5 = (const float*)d_in[15];
    float* out = (float*)d_out;
    char* ws = (char*)d_ws;

    const int B = in_sizes[0];

    hipLaunchKernelGGL(prep_kernel, dim3(256), dim3(256), 0, stream,
                       w2, w3, w4, b2, b3, b4, w5, ws);

    const int nblocks = (B + 3) >> 2;
    hipLaunchKernelGGL(fused_kernel, dim3(nblocks), dim3(512), 0, stream,
                       user_idxs, item_idxs, uidx, iidx, uemb, iemb,
                       w1, b1, b5, ws, out, B);
}

// Round 4
// 638.172 us; speedup vs baseline: 21.4614x; 1.3620x over previous
//
#include <hip/hip_runtime.h>
#include <math.h>

typedef short v8s __attribute__((ext_vector_type(8)));
typedef float v4f __attribute__((ext_vector_type(4)));
typedef unsigned int v4u __attribute__((ext_vector_type(4)));
typedef unsigned short us;
typedef unsigned int uu;

#define MFMA16(a,b,c) __builtin_amdgcn_mfma_f32_16x16x32_bf16((a),(b),(c),0,0,0)

// ---------------- workspace layout (fragment-linear) ----------------
// w3f: [ksc 7][nt 13][lane 64][i 8]  A-frag: j=16nt+(l&15), k=32ksc+8(l>>4)+i
// w2f: [nt 13][lane 64][i 8]         A-frag: j=16nt+(l&15), k=8(l>>4)+i
// w4f: [p*2+jt 14][lane 64][i 8]     A-frag: j=16jt+(l&15), k=32p+8(l>>4)+i
#define W3F_ELEMS (7*13*512)
#define W2F_ELEMS (13*512)
#define W4F_ELEMS (14*512)
#define OFF_W3F 0
#define OFF_W2F (OFF_W3F + W3F_ELEMS*2)
#define OFF_W4F (OFF_W2F + W2F_ELEMS*2)
#define OFF_B2B (OFF_W4F + W4F_ELEMS*2)
#define OFF_B3B (OFF_B2B + 208*4)
#define OFF_B4B (OFF_B3B + 224*4)
#define OFF_W5B (OFF_B4B + 32*4)

__device__ __forceinline__ us f2bf(float f) {
    union { float f; unsigned int u; } v; v.f = f;
    unsigned int u = v.u + 0x7FFFu + ((v.u >> 16) & 1u);   // RNE
    return (us)(u >> 16);
}
__device__ __forceinline__ uu pack2bf(float a, float b) {
    return (uu)f2bf(a) | ((uu)f2bf(b) << 16);
}

// ---------------- prep: fp32 weights -> bf16 fragment layout in ws ----------------
__global__ void prep_kernel(const float* __restrict__ w2, const float* __restrict__ w3,
                            const float* __restrict__ w4, const float* __restrict__ b2,
                            const float* __restrict__ b3, const float* __restrict__ b4,
                            const float* __restrict__ w5, char* __restrict__ ws) {
    us* w3f = (us*)(ws + OFF_W3F);
    us* w2f = (us*)(ws + OFF_W2F);
    us* w4f = (us*)(ws + OFF_W4F);
    float* b2b = (float*)(ws + OFF_B2B);
    float* b3b = (float*)(ws + OFF_B3B);
    float* b4b = (float*)(ws + OFF_B4B);
    float* w5b = (float*)(ws + OFF_W5B);

    const int gid = blockIdx.x * blockDim.x + threadIdx.x;
    const int stride = gridDim.x * blockDim.x;

    for (int idx = gid; idx < W3F_ELEMS; idx += stride) {
        int i = idx & 7, lane = (idx >> 3) & 63, f = idx >> 9;
        int nt = f % 13, ksc = f / 13;
        int j = 16*nt + (lane & 15), k = 32*ksc + 8*(lane >> 4) + i;
        w3f[idx] = f2bf((j < 200 && k < 200) ? w3[j*200 + k] : 0.f);
    }
    for (int idx = gid; idx < W2F_ELEMS; idx += stride) {
        int i = idx & 7, lane = (idx >> 3) & 63, nt = idx >> 9;
        int j = 16*nt + (lane & 15), k = 8*(lane >> 4) + i;
        w2f[idx] = f2bf((j < 200 && k < 20) ? w2[j*20 + k] : 0.f);
    }
    for (int idx = gid; idx < W4F_ELEMS; idx += stride) {
        int i = idx & 7, lane = (idx >> 3) & 63, f = idx >> 9;
        int p = f >> 1, jt = f & 1;
        int j = 16*jt + (lane & 15), k = 32*p + 8*(lane >> 4) + i;
        w4f[idx] = f2bf((j < 20 && k < 200) ? w4[j*200 + k] : 0.f);
    }
    for (int i = gid; i < 208; i += stride) b2b[i] = (i < 200) ? b2[i] : 0.f;
    for (int i = gid; i < 224; i += stride) b3b[i] = (i < 200) ? b3[i] : 0.f;
    for (int i = gid; i < 32;  i += stride) b4b[i] = (i < 20) ? b4[i] : 0.f;
    for (int i = gid; i < 32;  i += stride) w5b[i] = (i < 20) ? w5[i] : 0.f;
}

// ---------------- fused main kernel ----------------
// Block = 4 batch rows x 64 e = 256 MLP rows, 512 thr = 8 waves.
// Wave wv owns row-tiles t = 2wv, 2wv+1 (16 rows each) -> h1/h2/h3 wave-private.
// MFMA: A = weight frag, B = activation frag, D[feature][mlprow].
__global__ __launch_bounds__(512, 2) void fused_kernel(
    const int* __restrict__ user_idxs, const int* __restrict__ item_idxs,
    const int* __restrict__ uidx, const int* __restrict__ iidx,
    const float* __restrict__ uemb, const float* __restrict__ iemb,
    const float* __restrict__ w1, const float* __restrict__ b1,
    const float* __restrict__ b5p, const char* __restrict__ ws,
    float* __restrict__ out, int B)
{
    __shared__ us h2f[16*7*512];      // 114688 B : [tile][ksc][lane][8] B-frags
    __shared__ us wstage[2][13*512];  //  26624 B : w3 chunk double buffer
    __shared__ us h1f[16*512];        //  16384 B : h1 B-frags; later layer-4 scratch
    __shared__ float xbuf[8][64];     //   2048 B : gather sums; later mbuf
                                      // total 159744 <= 163840 -> 1 block/CU

    const int tid  = (int)threadIdx.x;
    const int lane = tid & 63;
    const int wv   = __builtin_amdgcn_readfirstlane(tid >> 6);
    const int bbase = blockIdx.x << 2;
    const int c = lane & 15;
    const int g = lane >> 4;

    const us* w3f = (const us*)(ws + OFF_W3F);
    const us* w2f = (const us*)(ws + OFF_W2F);
    const us* w4f = (const us*)(ws + OFF_W4F);
    const float* b2b = (const float*)(ws + OFF_B2B);
    const float* b3b = (const float*)(ws + OFF_B3B);
    const float* b4b = (const float*)(ws + OFF_B4B);
    const float* w5b = (const float*)(ws + OFF_W5B);

    // ---- prefetch w3 chunk 0 (T14 issue-early) ---------------------------
    v8s st0 = *(const v8s*)(w3f + tid*8);
    v8s st1 = {};
    if (tid < 320) st1 = *(const v8s*)(w3f + (512 + tid)*8);

    // ---- Phase 1: gather-sum; wave -> (b_local = wv>>1, table = wv&1) ----
    {
        int b = bbase + (wv >> 1); if (b >= B) b = B - 1;
        const int*   ntab = (wv & 1) ? iidx : uidx;
        const float* emb  = (wv & 1) ? iemb : uemb;
        const int idx0 = (wv & 1) ? item_idxs[b] : user_idxs[b];
        const int* nrow = ntab + idx0 * 100;
        float a0=0.f,a1=0.f,a2=0.f,a3=0.f,a4=0.f,a5=0.f,a6=0.f,a7=0.f;
        #pragma unroll 4
        for (int k = 0; k < 96; k += 8) {       // 32 loads in flight per body
            int4 i0 = *(const int4*)(nrow + k);
            int4 i1 = *(const int4*)(nrow + k + 4);
            a0 += emb[(size_t)i0.x * 64 + lane];
            a1 += emb[(size_t)i0.y * 64 + lane];
            a2 += emb[(size_t)i0.z * 64 + lane];
            a3 += emb[(size_t)i0.w * 64 + lane];
            a4 += emb[(size_t)i1.x * 64 + lane];
            a5 += emb[(size_t)i1.y * 64 + lane];
            a6 += emb[(size_t)i1.z * 64 + lane];
            a7 += emb[(size_t)i1.w * 64 + lane];
        }
        int4 it = *(const int4*)(nrow + 96);
        a0 += emb[(size_t)it.x * 64 + lane];
        a1 += emb[(size_t)it.y * 64 + lane];
        a2 += emb[(size_t)it.z * 64 + lane];
        a3 += emb[(size_t)it.w * 64 + lane];
        xbuf[wv][lane] = ((a0+a4)+(a1+a5)) + ((a2+a6)+(a3+a7));
    }

    // ---- zero h2f pad: ksc=6 slots 32..63 (k=208..223) of all 16 tiles ---
    {
        int t = tid >> 5, s = 32 + (tid & 31);
        v8s zz = {};
        *(v8s*)(h2f + (t*7 + 6)*512 + s*8) = zz;
    }
    __syncthreads();

    // ---- Layer 1 (2->20 fp32): one thread per MLP row -> h1f frags -------
    if (tid < 256) {
        const int rr = tid;
        const float xu = xbuf[2*(rr >> 6)][rr & 63];
        const float xv = xbuf[2*(rr >> 6) + 1][rr & 63];
        float h[20];
        #pragma unroll
        for (int j = 0; j < 20; ++j)
            h[j] = fmaxf(fmaf(xu, w1[2*j], fmaf(xv, w1[2*j+1], b1[j])), 0.f);
        us* tb = h1f + (rr >> 4)*512;
        const int cr = rr & 15;
        v4u o0 = { pack2bf(h[0],h[1]),  pack2bf(h[2],h[3]),
                   pack2bf(h[4],h[5]),  pack2bf(h[6],h[7]) };
        v4u o1 = { pack2bf(h[8],h[9]),  pack2bf(h[10],h[11]),
                   pack2bf(h[12],h[13]),pack2bf(h[14],h[15]) };
        v4u o2 = { pack2bf(h[16],h[17]),pack2bf(h[18],h[19]), 0u, 0u };
        v4u o3 = { 0u, 0u, 0u, 0u };
        *(v4u*)(tb + (0*16 + cr)*8) = o0;
        *(v4u*)(tb + (1*16 + cr)*8) = o1;
        *(v4u*)(tb + (2*16 + cr)*8) = o2;
        *(v4u*)(tb + (3*16 + cr)*8) = o3;
    }

    // ---- issue w2 fragment loads (global, L2) -----------------------------
    v8s af2[13];
    #pragma unroll
    for (int nt = 0; nt < 13; ++nt)
        af2[nt] = *(const v8s*)(w2f + (nt*64 + lane)*8);
    __syncthreads();   // h1f ready

    // ---- stage w3 chunk 0 (linear copy, conflict-free) ---------------------
    *(v8s*)(&wstage[0][tid*8]) = st0;
    if (tid < 320) *(v8s*)(&wstage[0][(512 + tid)*8]) = st1;

    // ---- Layer 2 (20->200): D[j][row] -> h2f (wave-private tiles) ---------
    #pragma unroll
    for (int m = 0; m < 2; ++m) {
        const int t = 2*wv + m;
        v8s bf1 = *(const v8s*)(h1f + t*512 + lane*8);
        #pragma unroll
        for (int nt = 0; nt < 13; ++nt) {
            v4f acc = {0.f,0.f,0.f,0.f};
            acc = MFMA16(af2[nt], bf1, acc);
            float4 bv = *(const float4*)(b2b + 16*nt + 4*g);
            const int r = 2*(nt & 1) + (g >> 1);
            uu* p = (uu*)(h2f + (t*7 + (nt >> 1))*512 + (r*16 + c)*8 + 4*(g & 1));
            p[0] = pack2bf(fmaxf(acc[0]+bv.x, 0.f), fmaxf(acc[1]+bv.y, 0.f));
            p[1] = pack2bf(fmaxf(acc[2]+bv.z, 0.f), fmaxf(acc[3]+bv.w, 0.f));
        }
    }
    __syncthreads();   // wstage[0] ready (h2f is wave-private, no sync needed)

    // ---- Layer 3 (200->200): 7 K-chunks, dbuf staged, 1 barrier/chunk -----
    v4f acc3[2][13];
    #pragma unroll
    for (int m = 0; m < 2; ++m)
        #pragma unroll
        for (int nt = 0; nt < 13; ++nt) acc3[m][nt] = (v4f){0.f,0.f,0.f,0.f};

    #pragma unroll 1
    for (int ksc = 0; ksc < 7; ++ksc) {
        const us* buf = wstage[ksc & 1];
        if (ksc < 6) {                    // issue prefetch of next chunk
            const us* src = w3f + (ksc + 1)*(13*512);
            st0 = *(const v8s*)(src + tid*8);
            if (tid < 320) st1 = *(const v8s*)(src + (512 + tid)*8);
        }
        v8s af[13];
        #pragma unroll
        for (int nt = 0; nt < 13; ++nt)
            af[nt] = *(const v8s*)(buf + (nt*64 + lane)*8);   // linear: no conflicts
        #pragma unroll
        for (int m = 0; m < 2; ++m) {
            v8s bf = *(const v8s*)(h2f + ((2*wv + m)*7 + ksc)*512 + lane*8);
            #pragma unroll
            for (int nt = 0; nt < 13; ++nt)
                acc3[m][nt] = MFMA16(af[nt], bf, acc3[m][nt]);
        }
        if (ksc < 6) {                    // write next chunk to other buffer
            us* nb = (us*)wstage[(ksc + 1) & 1];
            *(v8s*)(nb + tid*8) = st0;
            if (tid < 320) *(v8s*)(nb + (512 + tid)*8) = st1;
        }
        __syncthreads();
    }

    // ---- Layer 3 epilogue + Layer 4 (200->20), fused; scr = own h1f region -
    us* scr = h1f + wv*1024;              // wave-private: 2 m-frags of 512 elems
    v4f acc4[2][2];
    acc4[0][0] = (v4f){0,0,0,0}; acc4[0][1] = (v4f){0,0,0,0};
    acc4[1][0] = (v4f){0,0,0,0}; acc4[1][1] = (v4f){0,0,0,0};

    v8s a40 = *(const v8s*)(w4f + (0*2 + 0)*512 + lane*8);
    v8s a41 = *(const v8s*)(w4f + (0*2 + 1)*512 + lane*8);

    #pragma unroll
    for (int p = 0; p < 7; ++p) {
        v8s na0, na1;
        if (p < 6) {
            na0 = *(const v8s*)(w4f + ((p+1)*2 + 0)*512 + lane*8);
            na1 = *(const v8s*)(w4f + ((p+1)*2 + 1)*512 + lane*8);
        }
        #pragma unroll
        for (int m = 0; m < 2; ++m) {
            us* s = scr + m*512;
            #pragma unroll
            for (int tq = 0; tq < 2; ++tq) {
                const int nt = 2*p + tq;
                const int r = 2*tq + (g >> 1);
                uu* pp = (uu*)(s + (r*16 + c)*8 + 4*(g & 1));
                if (nt < 13) {
                    float4 bv = *(const float4*)(b3b + 16*nt + 4*g);
                    pp[0] = pack2bf(fmaxf(acc3[m][nt][0]+bv.x, 0.f),
                                    fmaxf(acc3[m][nt][1]+bv.y, 0.f));
                    pp[1] = pack2bf(fmaxf(acc3[m][nt][2]+bv.z, 0.f),
                                    fmaxf(acc3[m][nt][3]+bv.w, 0.f));
                } else {                   // k = 208..223 zero pad
                    pp[0] = 0u; pp[1] = 0u;
                }
            }
            v8s b4v = *(const v8s*)(s + lane*8);    // same-wave LDS dep
            acc4[m][0] = MFMA16(a40, b4v, acc4[m][0]);
            acc4[m][1] = MFMA16(a41, b4v, acc4[m][1]);
        }
        if (p < 6) { a40 = na0; a41 = na1; }
    }

    // ---- Layer 4 epilogue + Layer 5 (20->1) -> per-row value --------------
    float* mbuf = (float*)xbuf;            // xbuf dead
    {
        float4 b4lo = *(const float4*)(b4b + 4*g);
        float4 b4hi = *(const float4*)(b4b + 16 + 4*g);
        float4 w5lo = *(const float4*)(w5b + 4*g);
        float4 w5hi = *(const float4*)(w5b + 16 + 4*g);
        #pragma unroll
        for (int m = 0; m < 2; ++m) {
            float sacc = 0.f;
            #pragma unroll
            for (int q = 0; q < 4; ++q) {
                float h0 = fmaxf(acc4[m][0][q] + ((const float*)&b4lo)[q], 0.f);
                float h1 = fmaxf(acc4[m][1][q] + ((const float*)&b4hi)[q], 0.f);
                sacc = fmaf(h0, ((const float*)&w5lo)[q],
                       fmaf(h1, ((const float*)&w5hi)[q], sacc));
            }
            sacc += __shfl_xor(sacc, 16);
            sacc += __shfl_xor(sacc, 32);            // sum over g-groups
            if (lane < 16)
                mbuf[16*(2*wv + m) + c] = sacc;
        }
    }
    __syncthreads();

    // ---- mean over E=64 + sigmoid ------------------------------------------
    if (tid < 256) {
        float v = mbuf[tid];
        #pragma unroll
        for (int off = 1; off < 64; off <<= 1) v += __shfl_xor(v, off);
        const int b = bbase + (tid >> 6);
        if ((tid & 63) == 0 && b < B) {
            const float mval = v * (1.0f / 64.0f) + b5p[0];
            out[b] = 1.0f / (1.0f + expf(-mval));
        }
    }
}

extern "C" void kernel_launch(void* const* d_in, const int* in_sizes, int n_in,
                              void* d_out, int out_size, void* d_ws, size_t ws_size,
                              hipStream_t stream) {
    const int*   user_idxs = (const int*)d_in[0];
    const int*   item_idxs = (const int*)d_in[1];
    const int*   uidx      = (const int*)d_in[2];
    const int*   iidx      = (const int*)d_in[3];
    const float* uemb      = (const float*)d_in[4];
    const float* iemb      = (const float*)d_in[5];
    const float* w1 = (const float*)d_in[6];
    const float* b1 = (const float*)d_in[7];
    const float* w2 = (const float*)d_in[8];
    const float* b2 = (const float*)d_in[9];
    const float* w3 = (const float*)d_in[10];
    const float* b3 = (const float*)d_in[11];
    const float* w4 = (const float*)d_in[12];
    const float* b4 = (const float*)d_in[13];
    const float* w5 = (const float*)d_in[14];
    const float* b5 = (const float*)d_in[15];
    float* out = (float*)d_out;
    char* ws = (char*)d_ws;

    const int B = in_sizes[0];

    hipLaunchKernelGGL(prep_kernel, dim3(256), dim3(256), 0, stream,
                       w2, w3, w4, b2, b3, b4, w5, ws);

    const int nblocks = (B + 3) >> 2;
    hipLaunchKernelGGL(fused_kernel, dim3(nblocks), dim3(512), 0, stream,
                       user_idxs, item_idxs, uidx, iidx, uemb, iemb,
                       w1, b1, b5, ws, out, B);
}